// Round 5
// baseline (109.107 us; speedup 1.0000x reference)
//
#include <hip/hip_runtime.h>
#include <math.h>

#define BB 64
#define HH 30
#define WW 60
#define DD 64
#define NPIX 1800

// 16 col-bands / 8 row-bands = common refinement of the 6/10/15 pooling grids
__constant__ int c_colband[WW] = {0,0,0,0,0,0, 1,1,1,1, 2,2, 3,3,3, 4,4,4, 5,5, 6,6,6,6, 7,7,7,7,7,7,
                                  8,8,8,8,8,8, 9,9,9,9, 10,10, 11,11,11, 12,12,12, 13,13, 14,14,14,14, 15,15,15,15,15,15};
__constant__ int c_band_start[8] = {0,6,10,12,15,18,20,24};
__constant__ int c_band_cnt[8]   = {6,4,2,3,3,2,4,6};
// 20 column-region outputs (10 s0 + 6 s1 + 4 s2) composed from the 16 colband partials
__constant__ int c_first[20] = {0,1,3,5,7,8,9,11,13,15, 0,2,6,8,10,14, 0,4,8,12};
__constant__ int c_cnt[20]   = {1,2,2,2,1,1,2,2,2,1,   2,4,2,2,4,2,   4,4,4,4};
// colband -> s0/s1 col-region index
__constant__ int c_s0col[16] = {0,1,1,2,2,3,3,4,5,6,6,7,7,8,8,9};
__constant__ int c_s1col[16] = {0,0,1,1,1,1,2,2,3,3,4,4,4,4,5,5};
// rowband -> s0/s1 row-region index
__constant__ int c_s0row[8] = {0,1,1,2,2,3,3,4};
__constant__ int c_s1row[8] = {0,0,1,1,1,1,2,2};
// row-region -> row-band composition (first band, band count)
__constant__ int c_s0bf[5] = {0,1,3,5,7};
__constant__ int c_s0bc[5] = {1,2,2,2,1};
__constant__ int c_s1bf[3] = {0,2,6};
__constant__ int c_s1bc[3] = {2,4,2};
__constant__ int c_s2bf[2] = {0,4};

// ---------------- K1: band pooling of x (blocks 0..511, R3-proven, no atomics)
// ----------------     + E/u/v/s weight precompute (blocks 512..575, R4-proven)
__global__ __launch_bounds__(256) void k1_pool_E(
    const float* __restrict__ x, const float* __restrict__ qk_w,
    const float* __restrict__ qk_b, float* __restrict__ bandsums,
    float* __restrict__ ET_ws, float* __restrict__ u_ws,
    float* __restrict__ v_ws, float* __restrict__ s_ws)
{
    const int t = threadIdx.x;

    if (blockIdx.x >= 512) {
        // ET[e][d] = E[d][e] = sum_j Wq[j][d] * Wk[j][e]
        const int e = blockIdx.x - 512;
        if (t < 64) {
            float acc = 0.f;
#pragma unroll 8
            for (int jj = 0; jj < 64; ++jj)
                acc += qk_w[jj * 64 + t] * qk_w[(64 + jj) * 64 + e];
            ET_ws[e * 64 + t] = acc;
        } else if (e == 0 && t >= 64 && t < 128) {   // u[d] = Wq^T bk
            const int d = t - 64;
            float acc = 0.f;
            for (int jj = 0; jj < 64; ++jj) acc += qk_w[jj * 64 + d] * qk_b[64 + jj];
            u_ws[d] = acc;
        } else if (e == 0 && t >= 128 && t < 192) {  // v[e] = Wk^T bq
            const int e2 = t - 128;
            float acc = 0.f;
            for (int jj = 0; jj < 64; ++jj) acc += qk_w[(64 + jj) * 64 + e2] * qk_b[jj];
            v_ws[e2] = acc;
        } else if (e == 0 && t == 192) {             // s = bq . bk
            float acc = 0.f;
            for (int jj = 0; jj < 64; ++jj) acc += qk_b[jj] * qk_b[64 + jj];
            s_ws[0] = acc;
        }
        return;
    }

    __shared__ float pools[16 * 64];
    const int b = blockIdx.x >> 3;
    const int band = blockIdx.x & 7;
    const int j = t & 63;
    const int g = t >> 6;
    const int h0 = c_band_start[band];
    const int nr = c_band_cnt[band];

    float A0 = 0.f, A1 = 0.f, A2 = 0.f, A3 = 0.f;
    for (int r = 0; r < nr; ++r) {
        const float* xrow = x + ((size_t)(b * NPIX + (h0 + r) * WW) + g * 15) * DD;
        float v[15];
#pragma unroll
        for (int i = 0; i < 15; ++i) v[i] = xrow[i * DD + j];
        if ((g & 1) == 0) {   // colband widths 6,4,2,3 within this quarter
            A0 += ((v[0]+v[1])+(v[2]+v[3]))+(v[4]+v[5]);
            A1 += (v[6]+v[7])+(v[8]+v[9]);
            A2 += v[10]+v[11];
            A3 += (v[12]+v[13])+v[14];
        } else {              // widths 3,2,4,6
            A0 += (v[0]+v[1])+v[2];
            A1 += v[3]+v[4];
            A2 += (v[5]+v[6])+(v[7]+v[8]);
            A3 += ((v[9]+v[10])+(v[11]+v[12]))+(v[13]+v[14]);
        }
    }
    pools[(g * 4 + 0) * 64 + j] = A0;
    pools[(g * 4 + 1) * 64 + j] = A1;
    pools[(g * 4 + 2) * 64 + j] = A2;
    pools[(g * 4 + 3) * 64 + j] = A3;
    __syncthreads();

    float* outp = bandsums + (((size_t)b * 8 + band) * 20) * 64;
    for (int i = t; i < 20 * 64; i += 256) {
        const int c = i >> 6, d = i & 63;
        const int f = c_first[c], n = c_cnt[c];
        float s = 0.f;
        for (int q = 0; q < n; ++q) s += pools[(f + q) * 64 + d];
        outp[i] = s;
    }
}

// ---------------- K2: per-(b,rowband) — G once + fused dot/mask for the band's rows ----------------
// grid = BB*8, block = 256
__global__ __launch_bounds__(256) void k2_G_mask(
    const float* __restrict__ x, const float* __restrict__ score_w,
    const float* __restrict__ score_b, const float* __restrict__ bandsums,
    const float* __restrict__ ET_ws, const float* __restrict__ u_ws,
    const float* __restrict__ v_ws, const float* __restrict__ s_ws,
    const float* __restrict__ noise_x, const float* __restrict__ noise_r,
    float* __restrict__ out)
{
    __shared__ float ETs[4096];      // 16 KB
    __shared__ float R[20 * 64];     // 5 KB  this rowband's col-region sums
    __shared__ float XC[16 * 64];    // 4 KB  combined-weight vectors per cell
    __shared__ float Gl[16 * 64];    // 4 KB
    __shared__ float ul[64], vl[64];
    __shared__ float crow[16];
    __shared__ float attnv[360];     // up to 6 rows x 60 px
    __shared__ int cbt[64];

    const int b = blockIdx.x >> 3;
    const int rb = blockIdx.x & 7;
    const int t = threadIdx.x;
    const int lane = t & 63;
    const int g = t >> 6;
    const int h0 = c_band_start[rb];
    const int nr = c_band_cnt[rb];

    // phase A: stage ET, u, v, region sums (independent)
    for (int i = t; i < 4096; i += 256) ETs[i] = ET_ws[i];
    if (t < 64) ul[t] = u_ws[t];
    else if (t < 128) vl[t - 64] = v_ws[t - 64];
    if (t < 60) cbt[t] = c_colband[t];

    const int s0r = c_s0row[rb], s1r = c_s1row[rb], s2r = rb >> 2;
    const float* bs = bandsums + (size_t)b * 8 * 20 * 64;
    for (int i = t; i < 20 * 64; i += 256) {
        const int c = i >> 6;
        int f, n;
        if (c < 10)      { f = c_s0bf[s0r]; n = c_s0bc[s0r]; }
        else if (c < 16) { f = c_s1bf[s1r]; n = c_s1bc[s1r]; }
        else             { f = c_s2bf[s2r]; n = 4; }
        float s = 0.f;
        for (int q = 0; q < n; ++q) s += bs[(size_t)(f + q) * 20 * 64 + i];
        R[i] = s;
    }
    __syncthreads();

    // phase B: XC[cb] = sum_s (w_s / n_s) * regionsum_s
    const float w0n = score_w[0] * (1.0f / 36.0f);
    const float w1n = score_w[1] * (1.0f / 100.0f);
    const float w2n = score_w[2] * (1.0f / 225.0f);
    for (int i = t; i < 16 * 64; i += 256) {
        const int cb = i >> 6, d = i & 63;
        XC[i] = w0n * R[c_s0col[cb] * 64 + d]
              + w1n * R[(10 + c_s1col[cb]) * 64 + d]
              + w2n * R[(16 + (cb >> 2)) * 64 + d];
    }
    __syncthreads();

    // phase C: G[cb] = 0.125*(E . XC[cb] + wsum*u), c[cb] = 0.125*(v . XC[cb] + wsum*s) + sb
    {
        float et[64];
#pragma unroll
        for (int e = 0; e < 64; ++e) et[e] = ETs[e * 64 + lane];   // 2-way LDS aliasing = free

        const float wsum = score_w[0] + score_w[1] + score_w[2];
        const float sv = s_ws[0];
        const float sb = score_b[0];
        const float uval = ul[lane];
        const float vval = vl[lane];

#pragma unroll
        for (int ci = 0; ci < 4; ++ci) {
            const int cb = g * 4 + ci;
            const float4* xc4 = (const float4*)(XC + cb * 64);
            float acc = 0.f;
#pragma unroll
            for (int q = 0; q < 16; ++q) {
                const float4 xv = xc4[q];   // wave-uniform -> broadcast
                acc += xv.x * et[4*q] + xv.y * et[4*q+1] + xv.z * et[4*q+2] + xv.w * et[4*q+3];
            }
            Gl[cb * 64 + lane] = 0.125f * (acc + wsum * uval);

            float pv = vval * XC[cb * 64 + lane];
            pv += __shfl_xor(pv, 1, 64);  pv += __shfl_xor(pv, 2, 64);
            pv += __shfl_xor(pv, 4, 64);  pv += __shfl_xor(pv, 8, 64);
            pv += __shfl_xor(pv, 16, 64); pv += __shfl_xor(pv, 32, 64);
            if (lane == 0) crow[cb] = 0.125f * (pv + wsum * sv) + sb;
        }
    }
    __syncthreads();

    // phase D: per-pixel dot for each row of the band (16 lanes/pixel, float4)
    const int f16 = lane & 15;
    const int pg = lane >> 4;
    for (int r = 0; r < nr; ++r) {
        const float4* x4 = (const float4*)(x + (size_t)(b * NPIX + (h0 + r) * WW) * DD);
#pragma unroll
        for (int i = 0; i < 4; ++i) {
            const int pl = i * 4 + pg;
            if (pl < 15) {
                const int p = g * 15 + pl;
                const int cb = cbt[p];
                const float4 xv = x4[p * 16 + f16];
                const float4 gv = ((const float4*)Gl)[cb * 16 + f16];
                float s = xv.x * gv.x + xv.y * gv.y + xv.z * gv.z + xv.w * gv.w;
                s += __shfl_xor(s, 1, 64);
                s += __shfl_xor(s, 2, 64);
                s += __shfl_xor(s, 4, 64);
                s += __shfl_xor(s, 8, 64);
                if (f16 == 0) attnv[r * 60 + p] = s + crow[cb];
            }
        }
    }
    __syncthreads();

    // phase E: gumbel-sigmoid epilogue — pixels of this band are contiguous in memory
    const int base = b * NPIX + h0 * WW;
    for (int idx = t; idx < nr * 60; idx += 256) {
        const int pix = base + idx;
        const float a = attnv[idx];
        const float sg = 1.0f / (1.0f + expf(-a));
        const float gx = logf(sg + 1e-8f);
        const float gr = logf(1.0f - sg + 1e-8f);
        const float ux = noise_x[pix];
        const float ur = noise_r[pix];
        const float nx = -logf(-logf(ux + 1e-8f) + 1e-8f);
        const float nrv = -logf(-logf(ur + 1e-8f) + 1e-8f);
        const float INV_T = 1.0f / (0.03f + 1e-8f);
        const float A = (gx + nx) * INV_T;
        const float Rr = (gr + nrv) * INV_T;
        out[pix] = 1.0f / (1.0f + expf(Rr - A));
    }
}

extern "C" void kernel_launch(void* const* d_in, const int* in_sizes, int n_in,
                              void* d_out, int out_size, void* d_ws, size_t ws_size,
                              hipStream_t stream)
{
    const float* x       = (const float*)d_in[0];
    const float* qk_w    = (const float*)d_in[1];
    const float* qk_b    = (const float*)d_in[2];
    const float* score_w = (const float*)d_in[3];
    const float* score_b = (const float*)d_in[4];
    const float* noise_x = (const float*)d_in[5];
    const float* noise_r = (const float*)d_in[6];
    float* out = (float*)d_out;

    float* bandsums = (float*)d_ws;             // 64*8*20*64 = 655360 floats (2.62 MB)
    float* ET_ws = bandsums + 655360;           // 4096
    float* u_ws  = ET_ws + 4096;                // 64
    float* v_ws  = u_ws + 64;                   // 64
    float* s_ws  = v_ws + 64;                   // 1
    // ~2.64 MB total, fully overwritten each call (no memset needed)

    k1_pool_E<<<576, 256, 0, stream>>>(x, qk_w, qk_b, bandsums, ET_ws, u_ws, v_ws, s_ws);
    k2_G_mask<<<BB * 8, 256, 0, stream>>>(x, score_w, score_b, bandsums, ET_ws, u_ws, v_ws, s_ws,
                                          noise_x, noise_r, out);
}